// Round 1
// baseline (3654.604 us; speedup 1.0000x reference)
//
#include <hip/hip_runtime.h>
#include <math.h>

namespace {
constexpr int B = 512;
constexpr int N = 512;   // 8*8*8
constexpr int C = 96;
constexpr int CH = 32;   // channel chunk per qkv block
constexpr int RPB = 32;  // attention rows per block
constexpr int SROW = 516; // padded score-row stride (bank spread; 516%32=4 -> <=2-way)
}

// ---------------------------------------------------------------------------
// QKV: fused pointwise (1x1x1, full C input) + depthwise (3x3x3, SAME) conv.
// grid (B, 3 convs, C/CH chunks), block 256.
// Depthwise is per-channel, so channel-chunking is exact (no halo in C).
// ---------------------------------------------------------------------------
__global__ __launch_bounds__(256) void qkv_kernel(
    const float* __restrict__ x,
    const float* __restrict__ wq1, const float* __restrict__ bq1,
    const float* __restrict__ wk1, const float* __restrict__ bk1,
    const float* __restrict__ wv1, const float* __restrict__ bv1,
    const float* __restrict__ wqd, const float* __restrict__ bqd,
    const float* __restrict__ wkd, const float* __restrict__ bkd,
    const float* __restrict__ wvd, const float* __restrict__ bvd,
    float* __restrict__ qo, float* __restrict__ ko, float* __restrict__ vo)
{
    __shared__ __align__(16) float q1l[N * CH];    // 64 KB pointwise out chunk
    __shared__ __align__(16) float xl[64 * 97];    // x tile, stride 97 (bank spread)
    __shared__ __align__(16) float wl[C * CH];     // pointwise w, [ci][co]
    __shared__ float wdl[CH * 27];                 // depthwise w
    __shared__ float b1s[CH];
    __shared__ float bds[CH];

    const int b     = blockIdx.x;
    const int which = blockIdx.y;
    const int c0    = blockIdx.z * CH;
    const int tid   = threadIdx.x;

    const float* w1; const float* b1; const float* wd; const float* bd; float* out;
    if (which == 0)      { w1 = wq1; b1 = bq1; wd = wqd; bd = bqd; out = qo; }
    else if (which == 1) { w1 = wk1; b1 = bk1; wd = wkd; bd = bkd; out = ko; }
    else                 { w1 = wv1; b1 = bv1; wd = wvd; bd = bvd; out = vo; }

    // stage weights: wl[ci*CH + co] = w1[(c0+co)*C + ci]
    for (int i = tid; i < C * CH; i += 256) {
        int co = i & (CH - 1), ci = i >> 5;
        wl[i] = w1[(c0 + co) * C + ci];
    }
    for (int i = tid; i < CH * 27; i += 256) {
        int co = i / 27, t = i - co * 27;
        wdl[i] = wd[(c0 + co) * 27 + t];
    }
    if (tid < CH) { b1s[tid] = b1[c0 + tid]; bds[tid] = bd[c0 + tid]; }
    __syncthreads();

    // ---- phase 1: pointwise conv for this channel chunk, all 512 positions ----
    const float* xb = x + (size_t)b * N * C;
    for (int pt = 0; pt < N / 64; ++pt) {
        // stage 64 position rows of x (coalesced), stride-97 rows in LDS
        for (int i = tid; i < 64 * C; i += 256) {
            int r = i / C, ci = i - r * C;
            xl[r * 97 + ci] = xb[pt * 64 * C + i];
        }
        __syncthreads();
        const int cq = (tid & 7) * 4;   // 4 output channels per thread
        const int pr = tid >> 3;        // 32 position rows
        for (int half = 0; half < 2; ++half) {
            const int r = pr + half * 32;
            float a0 = b1s[cq + 0], a1 = b1s[cq + 1], a2 = b1s[cq + 2], a3 = b1s[cq + 3];
            const float* xr = &xl[r * 97];
            #pragma unroll 8
            for (int ci = 0; ci < C; ++ci) {
                const float xv = xr[ci];
                const float4 w4 = *(const float4*)&wl[ci * CH + cq];
                a0 += xv * w4.x; a1 += xv * w4.y; a2 += xv * w4.z; a3 += xv * w4.w;
            }
            *(float4*)&q1l[(pt * 64 + r) * CH + cq] = make_float4(a0, a1, a2, a3);
        }
        __syncthreads();
    }

    // ---- phase 2: depthwise 3x3x3 (SAME, cross-correlation) ----
    {
        const int co = tid & (CH - 1);
        const int pg = tid >> 5;        // 8 position groups
        float* ob = out + (size_t)b * N * C;
        for (int ii = 0; ii < 64; ++ii) {
            const int pos = pg * 64 + ii;
            const int pd = pos >> 6, ph = (pos >> 3) & 7, pw = pos & 7;
            float acc = bds[co];
            #pragma unroll
            for (int kd = 0; kd < 3; ++kd) {
                const int d2 = pd + kd - 1;
                if ((unsigned)d2 >= 8u) continue;
                #pragma unroll
                for (int kh = 0; kh < 3; ++kh) {
                    const int h2 = ph + kh - 1;
                    if ((unsigned)h2 >= 8u) continue;
                    #pragma unroll
                    for (int kw = 0; kw < 3; ++kw) {
                        const int w2 = pw + kw - 1;
                        if ((unsigned)w2 >= 8u) continue;
                        const int npos = (d2 << 6) + (h2 << 3) + w2;
                        acc += q1l[npos * CH + co] * wdl[co * 27 + kd * 9 + kh * 3 + kw];
                    }
                }
            }
            ob[(size_t)pos * C + (c0 + co)] = acc;
        }
    }
}

// ---------------------------------------------------------------------------
// Attention: per (batch, 32-row tile). Scores in LDS, fp32 softmax, PV.
// grid (B, N/RPB), block 256.
// ---------------------------------------------------------------------------
__global__ __launch_bounds__(256) void attn_kernel(
    const float* __restrict__ q, const float* __restrict__ k,
    const float* __restrict__ v, float* __restrict__ outp)
{
    __shared__ __align__(16) float ql[RPB * C];    // 12 KB
    __shared__ __align__(16) float s[RPB * SROW];  // ~66 KB

    const int b   = blockIdx.x;
    const int r0  = blockIdx.y * RPB;
    const int tid = threadIdx.x;
    const float scale = 0.10206207261596577f;  // 1/sqrt(96)

    const float* qb = q + ((size_t)b * N + r0) * C;
    const float* kb = k + (size_t)b * N * C;
    const float* vb = v + (size_t)b * N * C;

    for (int i = tid; i < RPB * C; i += 256) ql[i] = qb[i];
    __syncthreads();

    // ---- phase A: S = Q K^T * scale ----
    for (int half = 0; half < 2; ++half) {
        const int m = tid + half * 256;
        float acc[RPB];
        #pragma unroll
        for (int r = 0; r < RPB; ++r) acc[r] = 0.f;
        const float* krow = &kb[(size_t)m * C];
        for (int ci = 0; ci < C; ci += 4) {
            const float4 k4 = *(const float4*)&krow[ci];
            #pragma unroll
            for (int r = 0; r < RPB; ++r) {
                const float4 q4 = *(const float4*)&ql[r * C + ci];
                acc[r] += q4.x * k4.x + q4.y * k4.y + q4.z * k4.z + q4.w * k4.w;
            }
        }
        #pragma unroll
        for (int r = 0; r < RPB; ++r) s[r * SROW + m] = acc[r] * scale;
    }
    __syncthreads();

    // ---- phase B: softmax per row (8 lanes per row) ----
    {
        const int r = tid >> 3;
        const int g = tid & 7;
        float* row = &s[r * SROW];
        float mx = -1e30f;
        for (int j = g; j < N; j += 8) mx = fmaxf(mx, row[j]);
        #pragma unroll
        for (int off = 1; off < 8; off <<= 1) mx = fmaxf(mx, __shfl_xor(mx, off));
        float sum = 0.f;
        for (int j = g; j < N; j += 8) { float e = __expf(row[j] - mx); row[j] = e; sum += e; }
        #pragma unroll
        for (int off = 1; off < 8; off <<= 1) sum += __shfl_xor(sum, off);
        const float inv = 1.f / sum;
        for (int j = g; j < N; j += 8) row[j] *= inv;
    }
    __syncthreads();

    // ---- phase C: out = P V ----
    {
        const int r  = tid >> 3;        // 32 rows
        const int cg = tid & 7;         // 8 col groups x 12 cols = 96
        const int c0 = cg * 12;
        float acc[12];
        #pragma unroll
        for (int j = 0; j < 12; ++j) acc[j] = 0.f;
        const float* row = &s[r * SROW];
        for (int m = 0; m < N; ++m) {
            const float p = row[m];
            const float4* v4 = (const float4*)&vb[(size_t)m * C + c0];
            const float4 a = v4[0], bb = v4[1], cc = v4[2];
            acc[0] += p * a.x;  acc[1] += p * a.y;  acc[2]  += p * a.z;  acc[3]  += p * a.w;
            acc[4] += p * bb.x; acc[5] += p * bb.y; acc[6]  += p * bb.z; acc[7]  += p * bb.w;
            acc[8] += p * cc.x; acc[9] += p * cc.y; acc[10] += p * cc.z; acc[11] += p * cc.w;
        }
        float* ob = outp + ((size_t)b * N + (r0 + r)) * C + c0;
        #pragma unroll
        for (int j = 0; j < 12; ++j) ob[j] = acc[j];
    }
}

extern "C" void kernel_launch(void* const* d_in, const int* in_sizes, int n_in,
                              void* d_out, int out_size, void* d_ws, size_t ws_size,
                              hipStream_t stream) {
    const float* x   = (const float*)d_in[0];
    const float* wq1 = (const float*)d_in[1];
    const float* bq1 = (const float*)d_in[2];
    const float* wk1 = (const float*)d_in[3];
    const float* bk1 = (const float*)d_in[4];
    const float* wv1 = (const float*)d_in[5];
    const float* bv1 = (const float*)d_in[6];
    const float* wqd = (const float*)d_in[7];
    const float* bqd = (const float*)d_in[8];
    const float* wkd = (const float*)d_in[9];
    const float* bkd = (const float*)d_in[10];
    const float* wvd = (const float*)d_in[11];
    const float* bvd = (const float*)d_in[12];

    float* ws = (float*)d_ws;
    const size_t plane = (size_t)B * N * C;   // 25,165,824 floats
    float* q = ws;
    float* k = ws + plane;
    float* v = ws + 2 * plane;

    dim3 g1(B, 3, C / CH);
    qkv_kernel<<<g1, 256, 0, stream>>>(x, wq1, bq1, wk1, bk1, wv1, bv1,
                                       wqd, bqd, wkd, bkd, wvd, bvd, q, k, v);

    dim3 g2(B, N / RPB);
    attn_kernel<<<g2, 256, 0, stream>>>(q, k, v, (float*)d_out);
}

// Round 3
// 399.940 us; speedup vs baseline: 9.1379x; 9.1379x over previous
//
#include <hip/hip_runtime.h>
#include <math.h>

typedef _Float16 f16;
typedef _Float16 f16x2 __attribute__((ext_vector_type(2)));
typedef _Float16 f16x8 __attribute__((ext_vector_type(8)));
typedef float f32x4 __attribute__((ext_vector_type(4)));

union F2U { f16x2 h; unsigned u; };
union U4H { uint4 q; f16x2 h[4]; f16 f[8]; };

__device__ __forceinline__ f16x2 uAsH(unsigned u) { F2U c; c.u = u; return c.h; }
__device__ __forceinline__ unsigned hAsU(f16x2 h) { F2U c; c.h = h; return c.u; }

constexpr size_t PL = (size_t)512 * 512 * 96;

// ---------------------------------------------------------------------------
// K1: fused pointwise 1x1x1 conv as one GEMM [B*N,96] x [96, 288] (q1|k1|v1).
// Output: q1,k1 as [b][n][c] f16 (via LDS repack); v1 as [b][c][n] f16 direct.
// grid 4096 (64-row tiles), block 256 (4 waves, wave = 16 rows x 288 cols).
// ---------------------------------------------------------------------------
__global__ __launch_bounds__(256) void k1_pointwise(
    const float* __restrict__ x,
    const float* __restrict__ wq1, const float* __restrict__ bq1,
    const float* __restrict__ wk1, const float* __restrict__ bk1,
    const float* __restrict__ wv1, const float* __restrict__ bv1,
    f16* __restrict__ q1, f16* __restrict__ k1, f16* __restrict__ v1)
{
    __shared__ __align__(16) char sm[74368];
    f16*   Ah = (f16*)sm;                  // [64][104]
    f16*   Bw = (f16*)(sm + 13312);        // [288][104]
    float* bl = (float*)(sm + 73216);      // [288]
    f16*   rep = (f16*)(sm + 13312);       // overlay on Bw: [64][200]

    const int tid  = threadIdx.x;
    const int tile = blockIdx.x;
    const int bb   = tile >> 3;
    const int n0   = (tile & 7) * 64;
    const float* xb = x + (size_t)tile * 64 * 96;

    // stage A: 64x96 f32 -> f16 [64][104]
    #pragma unroll
    for (int it = 0; it < 6; ++it) {
        int i = tid * 4 + it * 1024;
        float4 v4 = *(const float4*)(xb + i);
        int r = i / 96, c = i % 96;
        f16x2 h01 = { (f16)v4.x, (f16)v4.y };
        f16x2 h23 = { (f16)v4.z, (f16)v4.w };
        uint2 st; st.x = hAsU(h01); st.y = hAsU(h23);
        *(uint2*)(Ah + r * 104 + c) = st;
    }
    // stage B: 3 x [96 out][96 in] f32 -> [288][104] f16
    #pragma unroll
    for (int it = 0; it < 27; ++it) {
        int i = tid * 4 + it * 1024;           // over 27648
        int a = i / 9216, rem = i % 9216;
        int co = rem / 96, ci = rem % 96;
        const float* wsrc = (a == 0) ? wq1 : ((a == 1) ? wk1 : wv1);
        float4 v4 = *(const float4*)(wsrc + rem);
        f16x2 h01 = { (f16)v4.x, (f16)v4.y };
        f16x2 h23 = { (f16)v4.z, (f16)v4.w };
        uint2 st; st.x = hAsU(h01); st.y = hAsU(h23);
        *(uint2*)(Bw + (a * 96 + co) * 104 + ci) = st;
    }
    for (int i = tid; i < 288; i += 256) {
        const float* bsrc = (i < 96) ? bq1 : ((i < 192) ? bk1 : bv1);
        bl[i] = bsrc[i % 96];
    }
    __syncthreads();

    const int wv_ = tid >> 6, lane = tid & 63, lr = lane & 15, lk = lane >> 4;

    f32x4 acc[18];
    #pragma unroll
    for (int i = 0; i < 18; ++i) acc[i] = f32x4{0.f, 0.f, 0.f, 0.f};

    #pragma unroll
    for (int ks = 0; ks < 3; ++ks) {
        f16x8 a = *(const f16x8*)(Ah + (wv_ * 16 + lr) * 104 + ks * 32 + lk * 8);
        #pragma unroll
        for (int cg = 0; cg < 18; ++cg) {
            f16x8 b8 = *(const f16x8*)(Bw + (cg * 16 + lr) * 104 + ks * 32 + lk * 8);
            acc[cg] = __builtin_amdgcn_mfma_f32_16x16x32_f16(a, b8, acc[cg], 0, 0, 0);
        }
    }
    __syncthreads();  // all MFMA reads of Bw done before rep overlays it

    #pragma unroll
    for (int cg = 0; cg < 18; ++cg) {
        float bv = bl[cg * 16 + lr];
        float o0 = acc[cg][0] + bv, o1 = acc[cg][1] + bv;
        float o2 = acc[cg][2] + bv, o3 = acc[cg][3] + bv;
        if (cg >= 12) {
            int c = (cg - 12) * 16 + lr;
            f16x2 h01 = { (f16)o0, (f16)o1 };
            f16x2 h23 = { (f16)o2, (f16)o3 };
            uint2 st; st.x = hAsU(h01); st.y = hAsU(h23);
            *(uint2*)(v1 + ((size_t)bb * 96 + c) * 512 + n0 + wv_ * 16 + lk * 4) = st;
        } else {
            int rr = wv_ * 16 + lk * 4, cc2 = cg * 16 + lr;
            rep[(rr + 0) * 200 + cc2] = (f16)o0;
            rep[(rr + 1) * 200 + cc2] = (f16)o1;
            rep[(rr + 2) * 200 + cc2] = (f16)o2;
            rep[(rr + 3) * 200 + cc2] = (f16)o3;
        }
    }
    __syncthreads();
    #pragma unroll
    for (int it = 0; it < 6; ++it) {
        int i = tid * 8 + it * 2048;            // over [64][192] = 12288
        int r = i / 192, c = i % 192;
        uint4 d4 = *(const uint4*)(rep + r * 200 + c);
        f16* dst = ((c < 96) ? q1 : k1) + ((size_t)bb * 512 + n0 + r) * 96 + (c % 96);
        *(uint4*)dst = d4;
    }
}

// ---------------------------------------------------------------------------
// K2: depthwise 3x3x3 SAME conv, f16. grid (512 batches, 3 convs), block 512.
//  which 0/1 (q,k): slab [512 pos][104 c], thread=pos, packed-f16 channel pairs.
//  which 2   (v):   slab [96 c][512 pos], unit=(c,d,h), w-row regs; out [c][n].
// ---------------------------------------------------------------------------
__global__ __launch_bounds__(512) void k2_depthwise(
    const float* __restrict__ wqd, const float* __restrict__ bqd,
    const float* __restrict__ wkd, const float* __restrict__ bkd,
    const float* __restrict__ wvd, const float* __restrict__ bvd,
    const f16* __restrict__ q1, const f16* __restrict__ k1, const f16* __restrict__ v1,
    f16* __restrict__ qo, f16* __restrict__ ko, f16* __restrict__ vo)
{
    __shared__ __align__(16) char sm[112128];
    const int tid = threadIdx.x;
    const int b = blockIdx.x;
    const int which = blockIdx.y;

    if (which < 2) {
        f16*      slab = (f16*)sm;                   // [512][104]
        unsigned* wdh  = (unsigned*)(sm + 106496);   // [27][48] u32 = [27][96] f16
        float*    bl   = (float*)(sm + 111680);      // [96]
        const f16* sb = ((which == 0) ? q1 : k1) + (size_t)b * 512 * 96;
        const float* wg = (which == 0) ? wqd : wkd;
        const float* bg = (which == 0) ? bqd : bkd;

        #pragma unroll
        for (int it = 0; it < 12; ++it) {
            int i = tid * 8 + it * 4096;             // f16 idx over [512][96]
            int r = i / 96, c = i % 96;
            *(uint4*)(slab + r * 104 + c) = *(const uint4*)(sb + i);
        }
        for (int ii = tid; ii < 2592; ii += 512) {
            int c = ii / 27, t2 = ii % 27;
            ((f16*)wdh)[t2 * 96 + c] = (f16)wg[ii];
        }
        if (tid < 96) bl[tid] = bg[tid];
        __syncthreads();

        const int pos = tid;
        const int d = pos >> 6, h = (pos >> 3) & 7, w = pos & 7;
        int npoff[27]; unsigned vmask[27];
        #pragma unroll
        for (int kd = 0; kd < 3; ++kd)
        #pragma unroll
        for (int kh = 0; kh < 3; ++kh)
        #pragma unroll
        for (int kw = 0; kw < 3; ++kw) {
            int t2 = kd * 9 + kh * 3 + kw;
            int d2 = d + kd - 1, h2 = h + kh - 1, w2 = w + kw - 1;
            bool valid = ((unsigned)d2 < 8u) && ((unsigned)h2 < 8u) && ((unsigned)w2 < 8u);
            int np = d2 * 64 + h2 * 8 + w2;
            npoff[t2] = valid ? np * 104 : 0;
            vmask[t2] = valid ? 0xFFFFFFFFu : 0u;
        }
        f16* outb = ((which == 0) ? qo : ko) + (size_t)b * 512 * 96;
        #pragma unroll
        for (int cc = 0; cc < 12; ++cc) {
            f16x2 a0[4], a1[4], a2[4];
            #pragma unroll
            for (int p = 0; p < 4; ++p) {
                a0[p] = f16x2{0, 0}; a1[p] = f16x2{0, 0}; a2[p] = f16x2{0, 0};
            }
            #pragma unroll
            for (int t2 = 0; t2 < 27; ++t2) {
                U4H rw; rw.q = *(const uint4*)(slab + npoff[t2] + cc * 8);
                unsigned vm = vmask[t2];
                #pragma unroll
                for (int p = 0; p < 4; ++p) {
                    f16x2 w2 = uAsH(wdh[t2 * 48 + cc * 4 + p] & vm);
                    if (t2 / 9 == 0)      a0[p] = rw.h[p] * w2 + a0[p];
                    else if (t2 / 9 == 1) a1[p] = rw.h[p] * w2 + a1[p];
                    else                  a2[p] = rw.h[p] * w2 + a2[p];
                }
            }
            unsigned ow[4];
            #pragma unroll
            for (int p = 0; p < 4; ++p) {
                float lo = (float)a0[p].x + (float)a1[p].x + (float)a2[p].x + bl[cc * 8 + 2 * p];
                float hi = (float)a0[p].y + (float)a1[p].y + (float)a2[p].y + bl[cc * 8 + 2 * p + 1];
                f16x2 hp = { (f16)lo, (f16)hi };
                ow[p] = hAsU(hp);
            }
            *(uint4*)(outb + (size_t)pos * 96 + cc * 8) = make_uint4(ow[0], ow[1], ow[2], ow[3]);
        }
    } else {
        f16*      slab = (f16*)sm;                   // [96][512] linear
        unsigned* wdp  = (unsigned*)(sm + 98304);    // [96][27] {w,w} pairs
        float*    bl   = (float*)(sm + 108672);      // [96]
        const f16* sb = v1 + (size_t)b * 96 * 512;

        #pragma unroll
        for (int it = 0; it < 12; ++it) {
            int i = tid * 8 + it * 4096;
            *(uint4*)(slab + i) = *(const uint4*)(sb + i);
        }
        for (int ii = tid; ii < 2592; ii += 512) {
            int c = ii / 27, t2 = ii % 27;
            f16 hh = (f16)wvd[ii];
            f16x2 hp = { hh, hh };
            wdp[c * 27 + t2] = hAsU(hp);
        }
        if (tid < 96) bl[tid] = bvd[tid];
        __syncthreads();

        f16* outb = vo + (size_t)b * 96 * 512;
        #pragma unroll
        for (int j = 0; j < 12; ++j) {
            int u = tid + j * 512;
            int c = u >> 6, dh = u & 63;
            int dd = dh >> 3, hh2 = dh & 7;
            f16x2 A0[4], A1[4], A2[4];
            #pragma unroll
            for (int p = 0; p < 4; ++p) {
                A0[p] = f16x2{0, 0}; A1[p] = f16x2{0, 0}; A2[p] = f16x2{0, 0};
            }
            #pragma unroll
            for (int kd = 0; kd < 3; ++kd) {
                int d2 = dd + kd - 1;
                unsigned vd_ = ((unsigned)d2 < 8u) ? 0xFFFFFFFFu : 0u;
                #pragma unroll
                for (int kh = 0; kh < 3; ++kh) {
                    int h2 = hh2 + kh - 1;
                    unsigned vm = ((((unsigned)h2 < 8u) ? 0xFFFFFFFFu : 0u) & vd_);
                    int rowoff = vm ? ((d2 * 8 + h2) * 8) : 0;
                    uint4 rw = *(const uint4*)(slab + c * 512 + rowoff);
                    unsigned r0 = rw.x, r1 = rw.y, r2 = rw.z, r3 = rw.w;
                    unsigned ms0 = r0 << 16;
                    unsigned ms1 = (r1 << 16) | (r0 >> 16);
                    unsigned ms2 = (r2 << 16) | (r1 >> 16);
                    unsigned ms3 = (r3 << 16) | (r2 >> 16);
                    unsigned ms4 = r3 >> 16;
                    int t0 = kd * 9 + kh * 3;
                    f16x2 w0 = uAsH(wdp[c * 27 + t0]     & vm);
                    f16x2 w1 = uAsH(wdp[c * 27 + t0 + 1] & vm);
                    f16x2 w2 = uAsH(wdp[c * 27 + t0 + 2] & vm);
                    f16x2* acc = (kd == 0) ? A0 : ((kd == 1) ? A1 : A2);
                    acc[0] = uAsH(ms0) * w0 + acc[0];
                    acc[1] = uAsH(ms1) * w0 + acc[1];
                    acc[2] = uAsH(ms2) * w0 + acc[2];
                    acc[3] = uAsH(ms3) * w0 + acc[3];
                    acc[0] = uAsH(r0) * w1 + acc[0];
                    acc[1] = uAsH(r1) * w1 + acc[1];
                    acc[2] = uAsH(r2) * w1 + acc[2];
                    acc[3] = uAsH(r3) * w1 + acc[3];
                    acc[0] = uAsH(ms1) * w2 + acc[0];
                    acc[1] = uAsH(ms2) * w2 + acc[1];
                    acc[2] = uAsH(ms3) * w2 + acc[2];
                    acc[3] = uAsH(ms4) * w2 + acc[3];
                }
            }
            float bv = bl[c];
            unsigned ow[4];
            #pragma unroll
            for (int p = 0; p < 4; ++p) {
                float lo = (float)A0[p].x + (float)A1[p].x + (float)A2[p].x + bv;
                float hi = (float)A0[p].y + (float)A1[p].y + (float)A2[p].y + bv;
                f16x2 hp = { (f16)lo, (f16)hi };
                ow[p] = hAsU(hp);
            }
            *(uint4*)(outb + c * 512 + dh * 8) = make_uint4(ow[0], ow[1], ow[2], ow[3]);
        }
    }
}

// ---------------------------------------------------------------------------
// K3: flash attention, f16 MFMA. grid (512, 8), block 256 (4 waves x 16 rows).
// Q,K: [b][n][c]; V: [b][c][n] (k-contiguous B operand). Out fp32 [b][n][c].
// ---------------------------------------------------------------------------
__global__ __launch_bounds__(256) void k3_attn(
    const f16* __restrict__ qF, const f16* __restrict__ kF, const f16* __restrict__ vF,
    float* __restrict__ outp)
{
    __shared__ __align__(16) char sm[76800];
    f16* qs  = (f16*)sm;                 // [64][104]
    f16* ks0 = (f16*)(sm + 13312);       // 2 x [64][104]
    f16* vt0 = (f16*)(sm + 39936);       // 2 x [96][72]
    f16* ps  = (f16*)(sm + 67584);       // [4][16][72]
    float* os = (float*)sm;              // overlay: [4][16][100]

    const int tid = threadIdx.x;
    const int b = blockIdx.x, qt = blockIdx.y;
    const int wv_ = tid >> 6, lane = tid & 63, lr = lane & 15, lk = lane >> 4;

    const f16* qg = qF + ((size_t)b * 512 + qt * 64) * 96;
    const f16* kg = kF + (size_t)b * 512 * 96;
    const f16* vg = vF + (size_t)b * 96 * 512;

    const f16 scl = (f16)0.14724447f;    // 1/sqrt(96) * log2(e)
    const f16x2 sc2 = { scl, scl };

    #pragma unroll
    for (int it = 0; it < 3; ++it) {
        int i = tid * 8 + it * 2048;
        int r = i / 96, c = i % 96;
        U4H d4; d4.q = *(const uint4*)(qg + i);
        #pragma unroll
        for (int p = 0; p < 4; ++p) d4.h[p] = d4.h[p] * sc2;
        *(uint4*)(qs + r * 104 + c) = d4.q;
    }
    #pragma unroll
    for (int it = 0; it < 3; ++it) {
        int i = tid * 8 + it * 2048;
        int r = i / 96, c = i % 96;
        *(uint4*)(ks0 + r * 104 + c) = *(const uint4*)(kg + i);
        int cv = i >> 6, nn = i & 63;
        *(uint4*)(vt0 + cv * 72 + nn) = *(const uint4*)(vg + cv * 512 + nn);
    }
    __syncthreads();

    float m_[4], l_[4];
    f32x4 accO[6];
    #pragma unroll
    for (int r = 0; r < 4; ++r) { m_[r] = -1e30f; l_[r] = 0.f; }
    #pragma unroll
    for (int cg = 0; cg < 6; ++cg) accO[cg] = f32x4{0.f, 0.f, 0.f, 0.f};

    for (int t = 0; t < 8; ++t) {
        const int cur = t & 1;
        f16* ksC = ks0 + cur * 6656;
        f16* vtC = vt0 + cur * 6912;
        uint4 kn[3], vn[3];
        if (t < 7) {
            #pragma unroll
            for (int it = 0; it < 3; ++it) {
                int i = tid * 8 + it * 2048;
                kn[it] = *(const uint4*)(kg + (t + 1) * 6144 + i);
                int cv = i >> 6, nn = i & 63;
                vn[it] = *(const uint4*)(vg + cv * 512 + (t + 1) * 64 + nn);
            }
        }
        // S = Q K^T (scaled, log2 domain)
        f32x4 sa[4];
        #pragma unroll
        for (int f = 0; f < 4; ++f) sa[f] = f32x4{0.f, 0.f, 0.f, 0.f};
        #pragma unroll
        for (int ks3 = 0; ks3 < 3; ++ks3) {
            f16x8 a = *(const f16x8*)(qs + (wv_ * 16 + lr) * 104 + ks3 * 32 + lk * 8);
            #pragma unroll
            for (int f = 0; f < 4; ++f) {
                f16x8 b8 = *(const f16x8*)(ksC + (f * 16 + lr) * 104 + ks3 * 32 + lk * 8);
                sa[f] = __builtin_amdgcn_mfma_f32_16x16x32_f16(a, b8, sa[f], 0, 0, 0);
            }
        }
        // online softmax
        float rm[4];
        #pragma unroll
        for (int r = 0; r < 4; ++r)
            rm[r] = fmaxf(fmaxf(sa[0][r], sa[1][r]), fmaxf(sa[2][r], sa[3][r]));
        #pragma unroll
        for (int off = 1; off < 16; off <<= 1) {
            #pragma unroll
            for (int r = 0; r < 4; ++r) rm[r] = fmaxf(rm[r], __shfl_xor(rm[r], off));
        }
        float al[4];
        #pragma unroll
        for (int r = 0; r < 4; ++r) {
            float mn = fmaxf(m_[r], rm[r]);
            al[r] = exp2f(m_[r] - mn);
            m_[r] = mn;
        }
        float pv[4][4], rs[4];
        #pragma unroll
        for (int r = 0; r < 4; ++r) rs[r] = 0.f;
        #pragma unroll
        for (int f = 0; f < 4; ++f) {
            #pragma unroll
            for (int r = 0; r < 4; ++r) { pv[f][r] = exp2f(sa[f][r] - m_[r]); rs[r] += pv[f][r]; }
        }
        #pragma unroll
        for (int off = 1; off < 16; off <<= 1) {
            #pragma unroll
            for (int r = 0; r < 4; ++r) rs[r] += __shfl_xor(rs[r], off);
        }
        #pragma unroll
        for (int r = 0; r < 4; ++r) l_[r] = l_[r] * al[r] + rs[r];
        #pragma unroll
        for (int cg = 0; cg < 6; ++cg) {
            #pragma unroll
            for (int r = 0; r < 4; ++r) accO[cg][r] *= al[r];
        }
        // P -> LDS (per-wave), re-enter as A fragment
        f16* psw = ps + wv_ * 1152;      // 16*72
        #pragma unroll
        for (int f = 0; f < 4; ++f) {
            #pragma unroll
            for (int r = 0; r < 4; ++r)
                psw[(lk * 4 + r) * 72 + f * 16 + lr] = (f16)pv[f][r];
        }
        // O += P V
        #pragma unroll
        for (int ks2 = 0; ks2 < 2; ++ks2) {
            f16x8 pa = *(const f16x8*)(psw + lr * 72 + ks2 * 32 + lk * 8);
            #pragma unroll
            for (int cg = 0; cg < 6; ++cg) {
                f16x8 vb = *(const f16x8*)(vtC + (cg * 16 + lr) * 72 + ks2 * 32 + lk * 8);
                accO[cg] = __builtin_amdgcn_mfma_f32_16x16x32_f16(pa, vb, accO[cg], 0, 0, 0);
            }
        }
        // write next tile (issue-early / write-late)
        if (t < 7) {
            f16* ksN = ks0 + (cur ^ 1) * 6656;
            f16* vtN = vt0 + (cur ^ 1) * 6912;
            #pragma unroll
            for (int it = 0; it < 3; ++it) {
                int i = tid * 8 + it * 2048;
                int r = i / 96, c = i % 96;
                *(uint4*)(ksN + r * 104 + c) = kn[it];
                int cv = i >> 6, nn = i & 63;
                *(uint4*)(vtN + cv * 72 + nn) = vn[it];
            }
        }
        __syncthreads();
    }
    // epilogue: O / l, repack via LDS, coalesced fp32 stores
    float inv[4];
    #pragma unroll
    for (int r = 0; r < 4; ++r) inv[r] = 1.f / l_[r];
    float* osw = os + wv_ * 1600;
    #pragma unroll
    for (int cg = 0; cg < 6; ++cg) {
        #pragma unroll
        for (int r = 0; r < 4; ++r)
            osw[(lk * 4 + r) * 100 + cg * 16 + lr] = accO[cg][r] * inv[r];
    }
    float* og = outp + ((size_t)b * 512 + qt * 64 + wv_ * 16) * 96;
    #pragma unroll
    for (int it = 0; it < 6; ++it) {
        int j = lane * 4 + it * 256;
        int r = j / 96, c = j % 96;
        float4 o4 = *(const float4*)(osw + r * 100 + c);
        *(float4*)(og + (size_t)r * 96 + c) = o4;
    }
}

extern "C" void kernel_launch(void* const* d_in, const int* in_sizes, int n_in,
                              void* d_out, int out_size, void* d_ws, size_t ws_size,
                              hipStream_t stream) {
    const float* x   = (const float*)d_in[0];
    const float* wq1 = (const float*)d_in[1];
    const float* bq1 = (const float*)d_in[2];
    const float* wk1 = (const float*)d_in[3];
    const float* bk1 = (const float*)d_in[4];
    const float* wv1 = (const float*)d_in[5];
    const float* bv1 = (const float*)d_in[6];
    const float* wqd = (const float*)d_in[7];
    const float* bqd = (const float*)d_in[8];
    const float* wkd = (const float*)d_in[9];
    const float* bkd = (const float*)d_in[10];
    const float* wvd = (const float*)d_in[11];
    const float* bvd = (const float*)d_in[12];

    f16* ws = (f16*)d_ws;
    f16* q1 = ws;
    f16* k1 = ws + PL;
    f16* v1 = ws + 2 * PL;
    f16* q  = ws + 3 * PL;
    f16* k  = ws + 4 * PL;
    f16* v  = ws + 5 * PL;

    k1_pointwise<<<4096, 256, 0, stream>>>(x, wq1, bq1, wk1, bk1, wv1, bv1, q1, k1, v1);
    k2_depthwise<<<dim3(512, 3), 512, 0, stream>>>(wqd, bqd, wkd, bkd, wvd, bvd,
                                                   q1, k1, v1, q, k, v);
    k3_attn<<<dim3(512, 8), 256, 0, stream>>>(q, k, v, (float*)d_out);
}